// Round 1
// baseline (1736.566 us; speedup 1.0000x reference)
//
#include <hip/hip_runtime.h>
#include <math.h>

// Problem constants (B=2, H=8, S=2048, D=64)
#define BH_    16          // B*H
#define S_     2048
#define D_     64
#define QT     4           // queries per block
#define BLOCK  256
#define KPT    8           // keys per thread in phase 1 = S_/BLOCK
#define NEWTON_ITERS 16

__device__ __forceinline__ float comp(const float4& a, int u) {
  return u == 0 ? a.x : u == 1 ? a.y : u == 2 ? a.z : a.w;
}

__global__ __launch_bounds__(BLOCK)
void entmax_attn_kernel(const float* __restrict__ q,
                        const float* __restrict__ k,
                        const float* __restrict__ v,
                        float* __restrict__ out) {
  // sc: scores -> p -> (aliased) phase-4 partial sums. 32KB.
  __shared__ float sc[QT][S_];
  __shared__ float qs[QT][D_];

  const int t   = threadIdx.x;
  const int blk = blockIdx.x;
  const int bh  = blk >> 9;          // blk / (S_/QT)
  const int qt  = blk & 511;         // blk % (S_/QT)
  const size_t qoff = ((size_t)bh * S_ + (size_t)qt * QT) * D_;
  const float* qp = q + qoff;
  const float* kp = k + (size_t)bh * S_ * D_;
  const float* vp = v + (size_t)bh * S_ * D_;
  float* op = out + qoff;

  // ---- load q tile; fold scale (1/8) and the entmax /2 => *1/16
  if (t < QT * D_) ((float*)qs)[t] = qp[t] * 0.0625f;
  __syncthreads();

  // ---- phase 1: scores (pre-divided by 2). Thread t handles keys t+256*j.
  for (int j = 0; j < KPT; ++j) {
    const float* krow = kp + (size_t)(t + BLOCK * j) * D_;
    float a0 = 0.f, a1 = 0.f, a2 = 0.f, a3 = 0.f;
#pragma unroll
    for (int dc = 0; dc < D_; dc += 4) {
      float4 kv = *(const float4*)(krow + dc);
      float4 q0 = *(const float4*)&qs[0][dc];
      float4 q1 = *(const float4*)&qs[1][dc];
      float4 q2 = *(const float4*)&qs[2][dc];
      float4 q3 = *(const float4*)&qs[3][dc];
      a0 = fmaf(q0.x, kv.x, a0); a0 = fmaf(q0.y, kv.y, a0);
      a0 = fmaf(q0.z, kv.z, a0); a0 = fmaf(q0.w, kv.w, a0);
      a1 = fmaf(q1.x, kv.x, a1); a1 = fmaf(q1.y, kv.y, a1);
      a1 = fmaf(q1.z, kv.z, a1); a1 = fmaf(q1.w, kv.w, a1);
      a2 = fmaf(q2.x, kv.x, a2); a2 = fmaf(q2.y, kv.y, a2);
      a2 = fmaf(q2.z, kv.z, a2); a2 = fmaf(q2.w, kv.w, a2);
      a3 = fmaf(q3.x, kv.x, a3); a3 = fmaf(q3.y, kv.y, a3);
      a3 = fmaf(q3.z, kv.z, a3); a3 = fmaf(q3.w, kv.w, a3);
    }
    const int kk = t + BLOCK * j;   // stride-1 across lanes: conflict-free
    sc[0][kk] = a0; sc[1][kk] = a1; sc[2][kk] = a2; sc[3][kk] = a3;
  }
  __syncthreads();

  // ---- phase 2/3: one wave per query. Row max + Newton for tau, then p.
  {
    const int wave = t >> 6;        // query index 0..3
    const int lane = t & 63;
    float x[32];
#pragma unroll
    for (int i = 0; i < 8; ++i) {
      float4 r = *(const float4*)&sc[wave][lane * 4 + i * 256];
      x[i*4+0] = r.x; x[i*4+1] = r.y; x[i*4+2] = r.z; x[i*4+3] = r.w;
    }
    float m = -1e30f;
#pragma unroll
    for (int i = 0; i < 32; ++i) m = fmaxf(m, x[i]);
#pragma unroll
    for (int off = 32; off >= 1; off >>= 1)
      m = fmaxf(m, __shfl_xor(m, off, 64));
#pragma unroll
    for (int i = 0; i < 32; ++i) x[i] -= m;   // x = (z - max(z))/2, max now 0

    // Newton on f(tau) = sum max(x - tau, 0)^2 - 1, from tau = -1 (monotone
    // from below; S1 >= sqrt(S2) -> >= ~1 near the root, so no div-by-0).
    float tau = -1.0f;
    for (int it = 0; it < NEWTON_ITERS; ++it) {
      float s1 = 0.f, s2 = 0.f;
#pragma unroll
      for (int i = 0; i < 32; ++i) {
        float u = fmaxf(x[i] - tau, 0.f);
        s1 += u;
        s2 = fmaf(u, u, s2);
      }
#pragma unroll
      for (int off = 32; off >= 1; off >>= 1) {
        s1 += __shfl_xor(s1, off, 64);
        s2 += __shfl_xor(s2, off, 64);
      }
      tau += (s2 - 1.0f) / (2.0f * s1);
    }

    // p = clip(x - tau, 0)^2, write back over scores
#pragma unroll
    for (int i = 0; i < 8; ++i) {
      float u0 = fmaxf(x[i*4+0] - tau, 0.f);
      float u1 = fmaxf(x[i*4+1] - tau, 0.f);
      float u2 = fmaxf(x[i*4+2] - tau, 0.f);
      float u3 = fmaxf(x[i*4+3] - tau, 0.f);
      float4 r; r.x = u0*u0; r.y = u1*u1; r.z = u2*u2; r.w = u3*u3;
      *(float4*)&sc[wave][lane * 4 + i * 256] = r;
    }
  }
  __syncthreads();

  // ---- phase 4: out = p @ v. 16 key-groups x 16 dim-lanes (float4 dims).
  {
    const int d4 = t & 15;          // float4 column within D
    const int g  = t >> 4;          // key group, 128 keys each
    const float4* v4 = (const float4*)vp;
    float4 acc0 = {0,0,0,0}, acc1 = {0,0,0,0}, acc2 = {0,0,0,0}, acc3 = {0,0,0,0};
    const int k0 = g * 128;
    for (int kb = 0; kb < 128; kb += 4) {
      const int kk = k0 + kb;
      float4 p0 = *(const float4*)&sc[0][kk];
      float4 p1 = *(const float4*)&sc[1][kk];
      float4 p2 = *(const float4*)&sc[2][kk];
      float4 p3 = *(const float4*)&sc[3][kk];
      // entmax rows are sparse: skip 4-key blocks with zero support (exact).
      float ssum = (p0.x + p0.y + p0.z + p0.w) + (p1.x + p1.y + p1.z + p1.w)
                 + (p2.x + p2.y + p2.z + p2.w) + (p3.x + p3.y + p3.z + p3.w);
      if (ssum > 0.f) {
#pragma unroll
        for (int u = 0; u < 4; ++u) {
          float4 vv = v4[(size_t)(kk + u) * (D_ / 4) + d4];
          float c0 = comp(p0, u), c1 = comp(p1, u), c2 = comp(p2, u), c3 = comp(p3, u);
          acc0.x = fmaf(c0, vv.x, acc0.x); acc0.y = fmaf(c0, vv.y, acc0.y);
          acc0.z = fmaf(c0, vv.z, acc0.z); acc0.w = fmaf(c0, vv.w, acc0.w);
          acc1.x = fmaf(c1, vv.x, acc1.x); acc1.y = fmaf(c1, vv.y, acc1.y);
          acc1.z = fmaf(c1, vv.z, acc1.z); acc1.w = fmaf(c1, vv.w, acc1.w);
          acc2.x = fmaf(c2, vv.x, acc2.x); acc2.y = fmaf(c2, vv.y, acc2.y);
          acc2.z = fmaf(c2, vv.z, acc2.z); acc2.w = fmaf(c2, vv.w, acc2.w);
          acc3.x = fmaf(c3, vv.x, acc3.x); acc3.y = fmaf(c3, vv.y, acc3.y);
          acc3.z = fmaf(c3, vv.z, acc3.z); acc3.w = fmaf(c3, vv.w, acc3.w);
        }
      }
    }
    __syncthreads();                 // all p reads done; safe to overwrite sc
    float* red = &sc[0][0];          // red[g][qq][d] : 16*4*64 floats = 16KB
    *(float4*)&red[(g * QT + 0) * D_ + d4 * 4] = acc0;
    *(float4*)&red[(g * QT + 1) * D_ + d4 * 4] = acc1;
    *(float4*)&red[(g * QT + 2) * D_ + d4 * 4] = acc2;
    *(float4*)&red[(g * QT + 3) * D_ + d4 * 4] = acc3;
    __syncthreads();
    // final cross-group reduction: thread -> (qq, d)
    const int qq = t >> 6, d = t & 63;
    float sum = 0.f;
#pragma unroll
    for (int gg = 0; gg < 16; ++gg) sum += red[(gg * QT + qq) * D_ + d];
    op[qq * D_ + d] = sum;
  }
}

extern "C" void kernel_launch(void* const* d_in, const int* in_sizes, int n_in,
                              void* d_out, int out_size, void* d_ws, size_t ws_size,
                              hipStream_t stream) {
  const float* q = (const float*)d_in[0];
  const float* k = (const float*)d_in[1];
  const float* v = (const float*)d_in[2];
  float* out = (float*)d_out;
  dim3 grid(BH_ * (S_ / QT));   // 16 * 512 = 8192 blocks
  entmax_attn_kernel<<<grid, dim3(BLOCK), 0, stream>>>(q, k, v, out);
}

// Round 2
// 595.601 us; speedup vs baseline: 2.9157x; 2.9157x over previous
//
#include <hip/hip_runtime.h>
#include <math.h>

// Problem constants (B=2, H=8, S=2048, D=64)
#define BH_    16          // B*H
#define S_     2048
#define D_     64
#define QT     4           // queries per block
#define BLOCK  256
#define KPT    8           // keys per thread in phase 1 = S_/BLOCK
#define NEWTON_ITERS 16

__device__ __forceinline__ float comp(const float4& a, int u) {
  return u == 0 ? a.x : u == 1 ? a.y : u == 2 ? a.z : a.w;
}

// __launch_bounds__(256,4): cap VGPR ~128 so 4 waves/SIMD co-reside.
// R1 evidence: without it VGPR=256 + 265MB spill traffic, occupancy 12%.
__global__ __launch_bounds__(BLOCK, 4)
void entmax_attn_kernel(const float* __restrict__ q,
                        const float* __restrict__ k,
                        const float* __restrict__ v,
                        float* __restrict__ out) {
  // sc: scores -> p -> (aliased) phase-4 partial sums. 32KB.
  __shared__ float sc[QT][S_];
  __shared__ float qs[QT][D_];

  const int t   = threadIdx.x;
  const int blk = blockIdx.x;
  const int bh  = blk >> 9;          // blk / (S_/QT)
  const int qt  = blk & 511;         // blk % (S_/QT)
  const size_t qoff = ((size_t)bh * S_ + (size_t)qt * QT) * D_;
  const float* qp = q + qoff;
  const float* kp = k + (size_t)bh * S_ * D_;
  const float* vp = v + (size_t)bh * S_ * D_;
  float* op = out + qoff;

  // ---- load q tile; fold scale (1/8) and the entmax /2 => *1/16
  ((float*)qs)[t] = qp[t] * 0.0625f;   // QT*D_ == BLOCK
  __syncthreads();

  // ---- phase 1: scores (pre-divided by 2). Thread t handles keys t+256*j.
  for (int j = 0; j < KPT; ++j) {
    const float* krow = kp + (size_t)(t + BLOCK * j) * D_;
    float a0 = 0.f, a1 = 0.f, a2 = 0.f, a3 = 0.f;
    // unroll 4 (not 16): full unroll hoisted ~320 values -> VGPR blowup in R1
#pragma unroll 4
    for (int dc = 0; dc < D_; dc += 4) {
      float4 kv = *(const float4*)(krow + dc);
      float4 q0 = *(const float4*)&qs[0][dc];
      float4 q1 = *(const float4*)&qs[1][dc];
      float4 q2 = *(const float4*)&qs[2][dc];
      float4 q3 = *(const float4*)&qs[3][dc];
      a0 = fmaf(q0.x, kv.x, a0); a0 = fmaf(q0.y, kv.y, a0);
      a0 = fmaf(q0.z, kv.z, a0); a0 = fmaf(q0.w, kv.w, a0);
      a1 = fmaf(q1.x, kv.x, a1); a1 = fmaf(q1.y, kv.y, a1);
      a1 = fmaf(q1.z, kv.z, a1); a1 = fmaf(q1.w, kv.w, a1);
      a2 = fmaf(q2.x, kv.x, a2); a2 = fmaf(q2.y, kv.y, a2);
      a2 = fmaf(q2.z, kv.z, a2); a2 = fmaf(q2.w, kv.w, a2);
      a3 = fmaf(q3.x, kv.x, a3); a3 = fmaf(q3.y, kv.y, a3);
      a3 = fmaf(q3.z, kv.z, a3); a3 = fmaf(q3.w, kv.w, a3);
    }
    const int kk = t + BLOCK * j;   // stride-1 across lanes: conflict-free
    sc[0][kk] = a0; sc[1][kk] = a1; sc[2][kk] = a2; sc[3][kk] = a3;
  }
  __syncthreads();

  // ---- phase 2/3: one wave per query. Row max + Newton for tau, then p.
  {
    const int wave = t >> 6;        // query index 0..3
    const int lane = t & 63;
    // row cache: 8 float4 = 32 VGPRs, live set here ~45 regs total
    float4 xv[8];
#pragma unroll
    for (int i = 0; i < 8; ++i)
      xv[i] = *(const float4*)&sc[wave][lane * 4 + i * 256];

    float m = -1e30f;
#pragma unroll
    for (int i = 0; i < 8; ++i) {
      m = fmaxf(m, fmaxf(fmaxf(xv[i].x, xv[i].y), fmaxf(xv[i].z, xv[i].w)));
    }
#pragma unroll
    for (int off = 32; off >= 1; off >>= 1)
      m = fmaxf(m, __shfl_xor(m, off, 64));
#pragma unroll
    for (int i = 0; i < 8; ++i) {   // x = (z - max(z))/2, max now 0
      xv[i].x -= m; xv[i].y -= m; xv[i].z -= m; xv[i].w -= m;
    }

    // Newton on f(tau) = sum max(x - tau, 0)^2 - 1, from tau = -1 (monotone
    // from below; S1 >= sqrt(S2) -> ~>=1 near the root, so no div-by-0).
    float tau = -1.0f;
    for (int it = 0; it < NEWTON_ITERS; ++it) {
      float s1 = 0.f, s2 = 0.f;
#pragma unroll
      for (int i = 0; i < 8; ++i) {
        float u0 = fmaxf(xv[i].x - tau, 0.f);
        float u1 = fmaxf(xv[i].y - tau, 0.f);
        float u2 = fmaxf(xv[i].z - tau, 0.f);
        float u3 = fmaxf(xv[i].w - tau, 0.f);
        s1 += (u0 + u1) + (u2 + u3);
        s2 = fmaf(u0, u0, s2); s2 = fmaf(u1, u1, s2);
        s2 = fmaf(u2, u2, s2); s2 = fmaf(u3, u3, s2);
      }
#pragma unroll
      for (int off = 32; off >= 1; off >>= 1) {
        s1 += __shfl_xor(s1, off, 64);
        s2 += __shfl_xor(s2, off, 64);
      }
      tau += (s2 - 1.0f) / (2.0f * s1);
    }

    // p = clip(x - tau, 0)^2, write back over scores
#pragma unroll
    for (int i = 0; i < 8; ++i) {
      float u0 = fmaxf(xv[i].x - tau, 0.f);
      float u1 = fmaxf(xv[i].y - tau, 0.f);
      float u2 = fmaxf(xv[i].z - tau, 0.f);
      float u3 = fmaxf(xv[i].w - tau, 0.f);
      float4 r; r.x = u0*u0; r.y = u1*u1; r.z = u2*u2; r.w = u3*u3;
      *(float4*)&sc[wave][lane * 4 + i * 256] = r;
    }
  }
  __syncthreads();

  // ---- phase 4: out = p @ v. 16 key-groups x 16 dim-lanes (float4 dims).
  {
    const int d4 = t & 15;          // float4 column within D
    const int g  = t >> 4;          // key group, 128 keys each
    const float4* v4 = (const float4*)vp;
    float4 acc0 = {0,0,0,0}, acc1 = {0,0,0,0}, acc2 = {0,0,0,0}, acc3 = {0,0,0,0};
    const int k0 = g * 128;
    // unroll 2: keep live set ~60 regs (4 p-vecs + 4 acc-vecs + temps)
#pragma unroll 2
    for (int kb = 0; kb < 128; kb += 4) {
      const int kk = k0 + kb;
      float4 p0 = *(const float4*)&sc[0][kk];
      float4 p1 = *(const float4*)&sc[1][kk];
      float4 p2 = *(const float4*)&sc[2][kk];
      float4 p3 = *(const float4*)&sc[3][kk];
      // entmax rows are sparse: skip 4-key blocks with zero support (exact).
      float ssum = (p0.x + p0.y + p0.z + p0.w) + (p1.x + p1.y + p1.z + p1.w)
                 + (p2.x + p2.y + p2.z + p2.w) + (p3.x + p3.y + p3.z + p3.w);
      if (ssum > 0.f) {
#pragma unroll
        for (int u = 0; u < 4; ++u) {
          float4 vv = v4[(size_t)(kk + u) * (D_ / 4) + d4];
          float c0 = comp(p0, u), c1 = comp(p1, u), c2 = comp(p2, u), c3 = comp(p3, u);
          acc0.x = fmaf(c0, vv.x, acc0.x); acc0.y = fmaf(c0, vv.y, acc0.y);
          acc0.z = fmaf(c0, vv.z, acc0.z); acc0.w = fmaf(c0, vv.w, acc0.w);
          acc1.x = fmaf(c1, vv.x, acc1.x); acc1.y = fmaf(c1, vv.y, acc1.y);
          acc1.z = fmaf(c1, vv.z, acc1.z); acc1.w = fmaf(c1, vv.w, acc1.w);
          acc2.x = fmaf(c2, vv.x, acc2.x); acc2.y = fmaf(c2, vv.y, acc2.y);
          acc2.z = fmaf(c2, vv.z, acc2.z); acc2.w = fmaf(c2, vv.w, acc2.w);
          acc3.x = fmaf(c3, vv.x, acc3.x); acc3.y = fmaf(c3, vv.y, acc3.y);
          acc3.z = fmaf(c3, vv.z, acc3.z); acc3.w = fmaf(c3, vv.w, acc3.w);
        }
      }
    }
    __syncthreads();                 // all p reads done; safe to overwrite sc
    float* red = &sc[0][0];          // red[g][qq][d] : 16*4*64 floats = 16KB
    *(float4*)&red[(g * QT + 0) * D_ + d4 * 4] = acc0;
    *(float4*)&red[(g * QT + 1) * D_ + d4 * 4] = acc1;
    *(float4*)&red[(g * QT + 2) * D_ + d4 * 4] = acc2;
    *(float4*)&red[(g * QT + 3) * D_ + d4 * 4] = acc3;
    __syncthreads();
    // final cross-group reduction: thread -> (qq, d)
    const int qq = t >> 6, d = t & 63;
    float sum = 0.f;
#pragma unroll
    for (int gg = 0; gg < 16; ++gg) sum += red[(gg * QT + qq) * D_ + d];
    op[qq * D_ + d] = sum;
  }
}

extern "C" void kernel_launch(void* const* d_in, const int* in_sizes, int n_in,
                              void* d_out, int out_size, void* d_ws, size_t ws_size,
                              hipStream_t stream) {
  const float* q = (const float*)d_in[0];
  const float* k = (const float*)d_in[1];
  const float* v = (const float*)d_in[2];
  float* out = (float*)d_out;
  dim3 grid(BH_ * (S_ / QT));   // 16 * 512 = 8192 blocks
  entmax_attn_kernel<<<grid, dim3(BLOCK), 0, stream>>>(q, k, v, out);
}